// Round 2
// baseline (3496.005 us; speedup 1.0000x reference)
//
#include <hip/hip_runtime.h>

// GumbelCodebook: B=32, N=64, D=256, C=8192 — ALL I/O fp32 (reference dtypes).
// Outputs concatenated in d_out (float): quantized[B*N*D] | log_alpha[B*N*C] | z[B*N*C]
//
// Round 2: correct fp32 VALU baseline (round 1 failed: I mis-cast fp32 inputs as bf16
// -> random mantissa half-words decoded as bf16 NaNs).
//   k_zero      : zero qp accumulator in ws
//   k_transpose : codebook_w [D][C] -> wt [C][D] (coalesced reads in k_codebook)
//   k_logalpha  : log_alpha = einsum(bnd,ndc) — head (512 MB) read exactly once, coalesced
//   k_softmax   : z = softmax((la+g)/tau) reading la back from d_out (fp32)
//   k_codebook  : qp = z @ W^T (fp32 atomicAdd partials over 16 C-chunks)
//   k_posmap    : quantized = qp @ pos_map
//
// ws layout (floats): qp[524288] | wt[2097152]  (10.5 MB)

#define B_ 32
#define N_ 64
#define D_ 256
#define C_ 8192

__global__ __launch_bounds__(256) void k_zero(float* __restrict__ qp) {
    qp[blockIdx.x * 256 + threadIdx.x] = 0.0f;   // grid covers exactly B*N*D
}

__global__ __launch_bounds__(256) void k_transpose(const float* __restrict__ w,
                                                   float* __restrict__ wt) {
    // w: [D][C] -> wt: [C][D]. 64x64 tiles, LDS padded +1.
    __shared__ float t[64][65];
    const int c0 = blockIdx.x * 64;
    const int d0 = blockIdx.y * 64;
    const int col = threadIdx.x & 63;
    const int rbase = threadIdx.x >> 6;   // 0..3
#pragma unroll
    for (int i = 0; i < 16; i++) {
        int r = rbase + i * 4;            // d offset within tile
        t[r][col] = w[(size_t)(d0 + r) * C_ + (c0 + col)];
    }
    __syncthreads();
#pragma unroll
    for (int i = 0; i < 16; i++) {
        int r = rbase + i * 4;            // c offset within tile
        wt[(size_t)(c0 + r) * D_ + (d0 + col)] = t[col][r];
    }
}

__global__ __launch_bounds__(256) void k_logalpha(const float* __restrict__ logits,
                                                  const float* __restrict__ head,
                                                  float* __restrict__ out_la) {
    const int n = blockIdx.y;                              // 0..63
    const int c = blockIdx.x * 256 + threadIdx.x;          // 0..8191
    float acc[B_];
#pragma unroll
    for (int b = 0; b < B_; b++) acc[b] = 0.0f;

    const float* hp = head + (size_t)n * D_ * C_ + c;
#pragma unroll 4
    for (int d = 0; d < D_; d++) {
        float h = hp[(size_t)d * C_];                      // coalesced, read once
#pragma unroll
        for (int b = 0; b < B_; b++) {
            acc[b] += logits[(b * N_ + n) * D_ + d] * h;   // uniform -> s_load
        }
    }
#pragma unroll
    for (int b = 0; b < B_; b++) {
        out_la[(size_t)(b * N_ + n) * C_ + c] = acc[b];
    }
}

__global__ __launch_bounds__(256) void k_softmax(const float* __restrict__ la,
                                                 const float* __restrict__ gumbel,
                                                 const float* __restrict__ tau,
                                                 float* __restrict__ out_z) {
    const int row = blockIdx.x;             // b*N + n, 0..2047
    const int t = threadIdx.x;
    const float inv_tau = 1.0f / tau[0];

    const float* lap = la + (size_t)row * C_;
    const float* gp = gumbel + (size_t)row * C_;

    float s[32];
    float m = -1e30f;
#pragma unroll
    for (int i = 0; i < 32; i++) {
        int c = t + i * 256;
        float v = (lap[c] + gp[c]) * inv_tau;
        s[i] = v;
        m = fmaxf(m, v);
    }

    __shared__ float red[8];
#pragma unroll
    for (int off = 32; off > 0; off >>= 1) m = fmaxf(m, __shfl_down(m, off));
    if ((t & 63) == 0) red[t >> 6] = m;
    __syncthreads();
    if (t == 0) red[4] = fmaxf(fmaxf(red[0], red[1]), fmaxf(red[2], red[3]));
    __syncthreads();
    m = red[4];

    float sum = 0.0f;
#pragma unroll
    for (int i = 0; i < 32; i++) {
        float e = __expf(s[i] - m);
        s[i] = e;
        sum += e;
    }
#pragma unroll
    for (int off = 32; off > 0; off >>= 1) sum += __shfl_down(sum, off);
    __syncthreads();                        // all reads of red[4] (max) done
    if ((t & 63) == 0) red[t >> 6] = sum;
    __syncthreads();
    if (t == 0) red[4] = red[0] + red[1] + red[2] + red[3];
    __syncthreads();
    const float inv = 1.0f / red[4];

#pragma unroll
    for (int i = 0; i < 32; i++) {
        int c = t + i * 256;
        out_z[(size_t)row * C_ + c] = s[i] * inv;
    }
}

__global__ __launch_bounds__(256) void k_codebook(const float* __restrict__ z,
                                                  const float* __restrict__ wt,
                                                  float* __restrict__ qp) {
    const int n = blockIdx.x & 63;
    const int chunk = blockIdx.x >> 6;      // 0..15, 512 c each
    const int d = threadIdx.x;              // 0..255
    const int c0 = chunk * 512;

    float acc[B_];
#pragma unroll
    for (int b = 0; b < B_; b++) acc[b] = 0.0f;

    for (int j = 0; j < 256; j++) {
        int c = c0 + 2 * j;
        float w0 = wt[(size_t)c * D_ + d];          // coalesced, L2/L3-resident (8 MB)
        float w1 = wt[(size_t)(c + 1) * D_ + d];
#pragma unroll
        for (int b = 0; b < B_; b++) {
            // uniform 8B load -> s_load_dwordx2
            float2 zz = *(const float2*)(z + (size_t)(b * N_ + n) * C_ + c);
            acc[b] += zz.x * w0 + zz.y * w1;
        }
    }
#pragma unroll
    for (int b = 0; b < B_; b++) {
        atomicAdd(&qp[(b * N_ + n) * D_ + d], acc[b]);   // 16 adds/address
    }
}

__global__ __launch_bounds__(256) void k_posmap(const float* __restrict__ qp,
                                                const float* __restrict__ pm,
                                                float* __restrict__ out_q) {
    const int n = blockIdx.x;               // 0..63
    const int m = threadIdx.x;              // 0..255
    float acc[B_];
#pragma unroll
    for (int b = 0; b < B_; b++) acc[b] = 0.0f;

#pragma unroll 4
    for (int d = 0; d < D_; d++) {
        float p = pm[((size_t)n * D_ + d) * D_ + m];       // coalesced
#pragma unroll
        for (int b = 0; b < B_; b++) {
            acc[b] += qp[(b * N_ + n) * D_ + d] * p;       // uniform -> s_load
        }
    }
#pragma unroll
    for (int b = 0; b < B_; b++) {
        out_q[(size_t)(b * N_ + n) * D_ + m] = acc[b];
    }
}

extern "C" void kernel_launch(void* const* d_in, const int* in_sizes, int n_in,
                              void* d_out, int out_size, void* d_ws, size_t ws_size,
                              hipStream_t stream) {
    const float* logits   = (const float*)d_in[0];
    const float* head     = (const float*)d_in[1];
    const float* pos_map  = (const float*)d_in[2];
    const float* codebook = (const float*)d_in[3];
    const float* gumbel   = (const float*)d_in[4];
    const float* tau      = (const float*)d_in[5];

    float* out    = (float*)d_out;
    float* out_q  = out;                                  // [B,N,D]
    float* out_la = out + (size_t)B_ * N_ * D_;           // [B,N,C]
    float* out_z  = out_la + (size_t)B_ * N_ * C_;        // [B,N,C]

    float* ws = (float*)d_ws;
    float* qp = ws;                          // 524288 floats
    float* wt = ws + 524288;                 // 2097152 floats (10.5 MB total)

    k_zero<<<2048, 256, 0, stream>>>(qp);
    {
        dim3 g(C_ / 64, D_ / 64);
        k_transpose<<<g, 256, 0, stream>>>(codebook, wt);
    }
    {
        dim3 g(C_ / 256, N_);
        k_logalpha<<<g, 256, 0, stream>>>(logits, head, out_la);
    }
    k_softmax<<<B_ * N_, 256, 0, stream>>>(out_la, gumbel, tau, out_z);
    k_codebook<<<16 * N_, 256, 0, stream>>>(out_z, wt, qp);
    k_posmap<<<N_, 256, 0, stream>>>(qp, pos_map, out_q);
}